// Round 15
// baseline (417.367 us; speedup 1.0000x reference)
//
#include <hip/hip_runtime.h>

// ---------------------------------------------------------------------------
// GCN model, re-associated: per layer h = relu((A_hat @ h_prev) @ W^T + b);
// pool BEFORE gcn_out linear. Node features BF16 (fp32 accumulate), dinv
// folded into features. CSR via single-pass padded-region binning.
// Ledger: R9/R14 best+reproduced (320.8/324.4us); k_fused 56us x3,
//   L2-miss-latency-bound at 4 loads in flight (64-VGPR wall of (1024,8)).
//   Falsified: LDS atomics (R4, 14x), 8-wide@64VGPR (R6/R8, spills),
//   LDS-ids alone (R9, null), L2 window sort (R10, null), mega-kernel
//   (R11, spills), R3-style wave-per-node loop (R12/R13, 63us now).
// R15: trade threads for registers. 512-thr blocks, launch_bounds(512,4)
//   -> 2 blk/CU at a 128-VGPR budget (double the room; thread count was
//   never the limiter). 8-lane subgroup per node, lane owns 16 features;
//   8 edges/iter (ids via one ds_read_b128), 16 uint4 loads in flight
//   (~95 VGPR < 128). Serial latency chain halves. MFMA: 8 waves x 4
//   col-tiles (acc2[4], static idx). Same math order -> bit-identical.
// ---------------------------------------------------------------------------

typedef __attribute__((ext_vector_type(8))) short short8;   // MFMA A/B frag
typedef __attribute__((ext_vector_type(4))) float f32x4;    // MFMA C/D frag

#define BKT 64        // nodes per bucket
#define SL 16         // slices per bucket
#define CAP 192       // capacity per (bucket,slice) cell   (Poisson 64)
#define WCAP 2560     // csrf window per bucket (padded degs; Poisson 1024)
#define NBINBLK 2048  // k_bin grid
#define HROWS 65536   // h-buffer rows allocated (row N = dummy zero row)

// Head-weight bf16 arena offsets (elements)
#define HW_MLP0 0
#define HW_MLP1 65536
#define HW_MLO  131072
#define HW_GCNO 147456
#define HW_PW1  163840
#define HW_PW2  212992
#define HW_TOT  278528

__device__ __forceinline__ unsigned short f2bf(float f) {
    union { float f; unsigned u; } c; c.f = f;
    unsigned u = c.u;
    unsigned r = u + 0x7FFFu + ((u >> 16) & 1u);   // RNE
    return (unsigned short)(r >> 16);
}
__device__ __forceinline__ float bflo(unsigned w) {
    union { unsigned u; float f; } c; c.u = w << 16; return c.f;
}
__device__ __forceinline__ float bfhi(unsigned w) {
    union { unsigned u; float f; } c; c.u = w & 0xFFFF0000u; return c.f;
}

// zero line-padded cursors, pool, dummy rows; cnt[g] via binary search on
// sorted batch (no atomics); cast gcn_W -> swizzled bf16; cast ALL head
// weights -> flat bf16 arena Wh.
__global__ void k_init(int* cur, float* pool, float* cnt,
                       const float* __restrict__ gcnW, uint4* __restrict__ Wb,
                       const float* __restrict__ mlpW, const float* __restrict__ mloW,
                       const float* __restrict__ gcnoW, const float* __restrict__ pW1,
                       const float* __restrict__ pW2, unsigned short* __restrict__ Wh,
                       unsigned short* xb, unsigned short* bufA, unsigned short* bufB,
                       const int* __restrict__ batch, int M, int G, int N) {
    int i = blockIdx.x * 256 + threadIdx.x;
    if (i < M * 16) cur[i] = 0;
    if (i < G * 128) pool[i] = 0.f;
    if (i < G) {
        // cnt[i] = #nodes with batch==i (batch sorted ascending)
        int lo = 0, hi = N;
        while (lo < hi) { int m = (lo + hi) >> 1; if (batch[m] < i) lo = m + 1; else hi = m; }
        int lo2 = lo, hi2 = N;
        while (lo2 < hi2) { int m = (lo2 + hi2) >> 1; if (batch[m] < i + 1) lo2 = m + 1; else hi2 = m; }
        cnt[i] = (float)(lo2 - lo);
    }
    if (i < 192) {                       // zero dummy row N of the 3 h-buffers
        unsigned short* b = (i < 64) ? xb : (i < 128) ? bufA : bufB;
        *(unsigned*)(b + (size_t)N * 128 + (i & 63) * 2) = 0u;
    }
    if (i < 3 * 2048) {                  // gcn W cast: chunk c=k/8, row o, layer l
        int l = i >> 11, rem = i & 2047;
        int o = rem >> 4, c = rem & 15;
        const float4* s = (const float4*)(gcnW + (size_t)l * 16384 + o * 128 + c * 8);
        float4 a = s[0], b = s[1];
        uint4 v;
        v.x = ((unsigned)f2bf(a.y) << 16) | f2bf(a.x);
        v.y = ((unsigned)f2bf(a.w) << 16) | f2bf(a.z);
        v.z = ((unsigned)f2bf(b.y) << 16) | f2bf(b.x);
        v.w = ((unsigned)f2bf(b.w) << 16) | f2bf(b.z);
        Wb[(l << 11) | (o << 4) | (c ^ (o & 15))] = v;
    }
    int j = i - 8192;                    // head-weight flat cast, 8 elems/thread
    if (j >= 0 && j < (HW_TOT / 8)) {
        int e = j * 8;
        const float* src;
        if (e < HW_MLO)        src = mlpW  + e;
        else if (e < HW_GCNO)  src = mloW  + (e - HW_MLO);
        else if (e < HW_PW1)   src = gcnoW + (e - HW_GCNO);
        else if (e < HW_PW2)   src = pW1   + (e - HW_PW1);
        else                   src = pW2   + (e - HW_PW2);
        float4 a = *(const float4*)src;
        float4 b = *((const float4*)src + 1);
        uint4 v;
        v.x = ((unsigned)f2bf(a.y) << 16) | f2bf(a.x);
        v.y = ((unsigned)f2bf(a.w) << 16) | f2bf(a.z);
        v.z = ((unsigned)f2bf(b.y) << 16) | f2bf(b.x);
        v.w = ((unsigned)f2bf(b.w) << 16) | f2bf(b.z);
        *(uint4*)(Wh + e) = v;
    }
}

// Single-pass binning. Cursor cell = cur[cell*16] (one 64B line per cell);
// gbin position = cell*CAP + count (closed form).
__global__ __launch_bounds__(256) void k_bin(const int* __restrict__ row,
                                             const int* __restrict__ col,
                                             int* __restrict__ cur,
                                             unsigned* __restrict__ gbin,
                                             int E, int C) {
    const int x = blockIdx.x & (SL - 1);
    int e0 = blockIdx.x * C, e1 = min(E, e0 + C);
    for (int e = e0 + threadIdx.x; e < e1; e += 256) {
        int c = col[e];
        int cell = (c >> 6) * SL + x;
        int cnt = atomicAdd(&cur[cell << 4], 1);
        gbin[cell * CAP + cnt] = (unsigned)row[e] | ((unsigned)(c & 63) << 16);
    }
}

// One block per bucket: LDS histogram of 64 dsts -> (start,deg,dinv) with
// degs PADDED to x8 in the prefix scan; scatter 2B src ids; fill pad slots
// with dummy src N; fused x->bf16*dinv cast.
__global__ __launch_bounds__(256) void k_csr(const unsigned* __restrict__ gbin,
                                             const int* __restrict__ cur,
                                             int* __restrict__ rs,
                                             unsigned short* __restrict__ rd,
                                             float* __restrict__ dinv,
                                             unsigned short* __restrict__ csrf,
                                             const float* __restrict__ x,
                                             unsigned short* __restrict__ xb,
                                             int N) {
    const int b = blockIdx.x, t = threadIdx.x;
    __shared__ int hcnt[64], lcur[64], fills[SL];
    __shared__ float sdinv[64];
    if (t < 64) hcnt[t] = 0;
    if (t < SL) fills[t] = cur[(b * SL + t) << 4];
    __syncthreads();
    #pragma unroll 4
    for (int xx = 0; xx < SL; ++xx) {
        int cbase = (b * SL + xx) * CAP, fill = fills[xx];
        for (int i = t; i < fill; i += 256)
            atomicAdd(&hcnt[(gbin[cbase + i] >> 16) & 63], 1);
    }
    __syncthreads();
    if (t < 64) {
        int v = hcnt[t];
        int vp = (v + 7) & ~7;          // padded degree
        int xs = vp;
        #pragma unroll
        for (int off = 1; off < 64; off <<= 1) {
            int u = __shfl_up(xs, off, 64);
            if (t >= off) xs += u;
        }
        int excl = xs - vp;             // padded exclusive prefix (x8 aligned)
        lcur[t] = excl;
        float d = rsqrtf((float)v + 1.0f);
        sdinv[t] = d;
        int node = b * 64 + t;          // rs/rd/dinv sized NBK*64: always safe
        rs[node] = b * WCAP + excl;
        rd[node] = (unsigned short)v;
        dinv[node] = d;
    }
    __syncthreads();
    #pragma unroll 4
    for (int xx = 0; xx < SL; ++xx) {
        int cbase = (b * SL + xx) * CAP, fill = fills[xx];
        for (int i = t; i < fill; i += 256) {
            unsigned v = gbin[cbase + i];
            int p = atomicAdd(&lcur[(v >> 16) & 63], 1);
            csrf[b * WCAP + p] = (unsigned short)(v & 0xFFFFu);
        }
    }
    __syncthreads();
    if (t < 64) {                        // fill pad slots with dummy src N
        int v = hcnt[t], vp = (v + 7) & ~7;
        int base = lcur[t];              // == excl + v after scatter
        for (int p = v; p < vp; ++p)
            csrf[b * WCAP + base + (p - v)] = (unsigned short)N;
    }
    // fused x -> bf16*dinv cast (64 nodes x 16 chunks)
    const int node0 = b * 64;
    #pragma unroll
    for (int it = 0; it < 4; ++it) {
        int i = t + it * 256;              // 0..1023
        int nd = node0 + (i >> 4);
        if (nd < N) {
            int ch = i & 15;
            float d = sdinv[i >> 4];
            const float4* s = (const float4*)(x + (size_t)nd * 128 + ch * 8);
            float4 a = s[0], bb = s[1];
            uint4 o;
            o.x = ((unsigned)f2bf(d * a.y) << 16) | f2bf(d * a.x);
            o.y = ((unsigned)f2bf(d * a.w) << 16) | f2bf(d * a.z);
            o.z = ((unsigned)f2bf(d * bb.y) << 16) | f2bf(d * bb.x);
            o.w = ((unsigned)f2bf(d * bb.w) << 16) | f2bf(d * bb.z);
            *(uint4*)(xb + (size_t)nd * 128 + ch * 8) = o;
        }
    }
}

#define ACC8(vv, off) \
    acc[(off) + 0] += bflo(vv.x); acc[(off) + 1] += bfhi(vv.x); \
    acc[(off) + 2] += bflo(vv.y); acc[(off) + 3] += bfhi(vv.y); \
    acc[(off) + 4] += bflo(vv.z); acc[(off) + 5] += bfhi(vv.z); \
    acc[(off) + 6] += bflo(vv.w); acc[(off) + 7] += bfhi(vv.w);

// Fused per-layer kernel: block = 64 nodes = one MFMA tile, 512 thr/8 waves,
// 2 blocks/CU at launch_bounds(512,4) -> 128-VGPR budget.
// Gather: 8-lane subgroup per node; lane owns 16 features (2x uint4/row).
// 8 edges per iteration (one ds_read_b128 of ids), 16 uint4 loads in flight
// (~95 VGPR, fits the 128 budget with margin). Ids staged in LDS (lgkmcnt).
// MFMA: 8 waves = (row-tile rt = wv&3) x (col-half ch = wv>>2, 4 col-tiles).
// l=2 (pool != nullptr): skip C store, atomic segment-sum into pool.
// h (input) and C (output) MUST be distinct buffers (launcher ping-pongs).
__global__ __launch_bounds__(512, 4) void k_fused(
    const unsigned short* __restrict__ h,
    const uint4* __restrict__ Wb,
    const float* __restrict__ bias,
    const float* __restrict__ dscale,
    const float* __restrict__ dinv,
    const int* __restrict__ rs,
    const unsigned short* __restrict__ rd,
    const unsigned short* __restrict__ csrf,
    unsigned short* __restrict__ C,
    const int* __restrict__ batch,
    float* __restrict__ pool, int N) {
    __shared__ uint4 Wsh[2048];                 // 32 KB swizzled weights
    __shared__ unsigned short Ash[64][136];     // 17 KB padded A tile
    __shared__ unsigned short Ish[WCAP];        // 5 KB edge ids (padded x8)

    const int t = threadIdx.x;
    #pragma unroll
    for (int it = 0; it < 4; ++it)
        Wsh[t + it * 512] = Wb[t + it * 512];

    const int sub = t >> 3;                     // 0..63 subgroup = local row
    const int fg8 = t & 7;                      // feature group (16 elems)
    const int blk0 = blockIdx.x * 64;
    const int node = blk0 + sub;

    // ---- stage edge-id window into LDS (16B chunks, padded x8 -> exact) ----
    const int base = blockIdx.x * WCAP;
    const int ln = blk0 + 63;                   // rs/rd sized NBK*64: safe
    const int wcnt = (rs[ln] + ((rd[ln] + 7) & ~7)) - base;
    for (int i = t * 8; i < wcnt; i += 4096)
        *(uint4*)(&Ish[i]) = *(const uint4*)(csrf + base + i);
    __syncthreads();

    // ---- gather: acc[16] in regs, self-row init; ids from LDS; 8 edges/iter ----
    float acc[16];
    #pragma unroll
    for (int j = 0; j < 16; ++j) acc[j] = 0.f;
    const unsigned fgo = (unsigned)fg8 * 16u;   // element offset of lane's 16
    if (node < N) {
        const uint4 ha = *(const uint4*)(h + (size_t)node * 128u + fgo);
        const uint4 hb = *(const uint4*)(h + (size_t)node * 128u + fgo + 8u);
        ACC8(ha, 0); ACC8(hb, 8);
    }
    {
        const int stl = rs[node] - base;
        const int epl = stl + ((rd[node] + 7) & ~7);
        #pragma unroll 1
        for (int i = stl; i < epl; i += 8) {
            const uint4 iv = *(const uint4*)(&Ish[i]);   // 8 ids, ds_read_b128
            const unsigned s0 = (iv.x & 0xFFFFu) * 128u + fgo;
            const unsigned s1 = (iv.x >> 16)     * 128u + fgo;
            const unsigned s2 = (iv.y & 0xFFFFu) * 128u + fgo;
            const unsigned s3 = (iv.y >> 16)     * 128u + fgo;
            const unsigned s4 = (iv.z & 0xFFFFu) * 128u + fgo;
            const unsigned s5 = (iv.z >> 16)     * 128u + fgo;
            const unsigned s6 = (iv.w & 0xFFFFu) * 128u + fgo;
            const unsigned s7 = (iv.w >> 16)     * 128u + fgo;
            const uint4 a0 = *(const uint4*)(h + s0);
            const uint4 b0 = *(const uint4*)(h + s0 + 8u);
            const uint4 a1 = *(const uint4*)(h + s1);
            const uint4 b1 = *(const uint4*)(h + s1 + 8u);
            const uint4 a2 = *(const uint4*)(h + s2);
            const uint4 b2 = *(const uint4*)(h + s2 + 8u);
            const uint4 a3 = *(const uint4*)(h + s3);
            const uint4 b3 = *(const uint4*)(h + s3 + 8u);
            const uint4 a4 = *(const uint4*)(h + s4);
            const uint4 b4 = *(const uint4*)(h + s4 + 8u);
            const uint4 a5 = *(const uint4*)(h + s5);
            const uint4 b5 = *(const uint4*)(h + s5 + 8u);
            const uint4 a6 = *(const uint4*)(h + s6);
            const uint4 b6 = *(const uint4*)(h + s6 + 8u);
            const uint4 a7 = *(const uint4*)(h + s7);
            const uint4 b7 = *(const uint4*)(h + s7 + 8u);
            ACC8(a0, 0); ACC8(b0, 8);
            ACC8(a1, 0); ACC8(b1, 8);
            ACC8(a2, 0); ACC8(b2, 8);
            ACC8(a3, 0); ACC8(b3, 8);
            ACC8(a4, 0); ACC8(b4, 8);
            ACC8(a5, 0); ACC8(b5, 8);
            ACC8(a6, 0); ACC8(b6, 8);
            ACC8(a7, 0); ACC8(b7, 8);
        }
    }
    // ---- scale + pack to bf16 A-tile (2x uint4) ----
    {
        const float dn = (node < N) ? dinv[node] : 0.f;
        unsigned short ob[16];
        #pragma unroll
        for (int j = 0; j < 16; ++j) ob[j] = f2bf(acc[j] * dn);
        uint4 o0, o1;
        o0.x = ((unsigned)ob[1] << 16) | ob[0];
        o0.y = ((unsigned)ob[3] << 16) | ob[2];
        o0.z = ((unsigned)ob[5] << 16) | ob[4];
        o0.w = ((unsigned)ob[7] << 16) | ob[6];
        o1.x = ((unsigned)ob[9] << 16) | ob[8];
        o1.y = ((unsigned)ob[11] << 16) | ob[10];
        o1.z = ((unsigned)ob[13] << 16) | ob[12];
        o1.w = ((unsigned)ob[15] << 16) | ob[14];
        *(uint4*)(&Ash[sub][fg8 * 16]) = o0;
        *(uint4*)(&Ash[sub][fg8 * 16 + 8]) = o1;
    }
    __syncthreads();

    // ---- MFMA: 8 waves, wave = (rt, ch); 4 col-tiles per wave ----
    const int lane = t & 63;
    const int wv = t >> 6;                      // 0..7
    const int l15 = lane & 15, quad = lane >> 4;
    const int rt = wv & 3, ch = wv >> 2;
    f32x4 acc2[4];
    #pragma unroll
    for (int cc = 0; cc < 4; ++cc) acc2[cc] = (f32x4){0.f, 0.f, 0.f, 0.f};
    #pragma unroll
    for (int kiter = 0; kiter < 4; ++kiter) {
        short8 af = *(const short8*)(&Ash[rt * 16 + l15][kiter * 32 + quad * 8]);
        const int cswz = (kiter * 4 + quad) ^ l15;
        #pragma unroll
        for (int cc = 0; cc < 4; ++cc) {
            int ct = ch * 4 + cc;
            short8 bf = *(const short8*)(&Wsh[((ct * 16 + l15) << 4) | cswz]);
            acc2[cc] = __builtin_amdgcn_mfma_f32_16x16x32_bf16(af, bf, acc2[cc], 0, 0, 0);
        }
    }

    const int rbase = blk0 + rt * 16 + quad * 4;
    if (pool) {
        // l=2: relu + segment-sum into pool (rows sorted by graph)
        int gr[4];
        #pragma unroll
        for (int r = 0; r < 4; ++r)
            gr[r] = (rbase + r < N) ? batch[rbase + r] : -1;
        #pragma unroll
        for (int cc = 0; cc < 4; ++cc) {
            int colc = (ch * 4 + cc) * 16 + l15;
            float bcol = bias[colc];
            float s = 0.f; int gprev = -2;
            #pragma unroll
            for (int r = 0; r < 4; ++r) {
                if (gr[r] >= 0) {
                    float v = fmaxf(acc2[cc][r] + bcol, 0.f);
                    if (gr[r] == gprev) s += v;
                    else {
                        if (gprev >= 0) atomicAdd(&pool[(size_t)gprev * 128 + colc], s);
                        gprev = gr[r]; s = v;
                    }
                }
            }
            if (gprev >= 0) atomicAdd(&pool[(size_t)gprev * 128 + colc], s);
        }
    } else {
        float ds[4];
        #pragma unroll
        for (int r = 0; r < 4; ++r) {
            int rr = rbase + r;
            ds[r] = (dscale && rr < N) ? dscale[rr] : 1.f;
        }
        #pragma unroll
        for (int cc = 0; cc < 4; ++cc) {
            int colc = (ch * 4 + cc) * 16 + l15;
            float bcol = bias[colc];
            #pragma unroll
            for (int r = 0; r < 4; ++r) {
                int rr = rbase + r;
                if (rr < N) {
                    float v = fmaxf(acc2[cc][r] + bcol, 0.f) * ds[r];
                    C[(size_t)rr * 128 + colc] = f2bf(v);
                }
            }
        }
    }
}

// Fused head via MFMA: 16 graphs/block (M=16), 256 thr = 4 waves. Activations
// bf16 in LDS; B-frags from bf16 weight arena in global (L2-hot). Each wave
// owns 4 of 16 output-tiles per 256-out layer. fp32 accumulation throughout.
__global__ __launch_bounds__(256) void k_head(
    const unsigned short* __restrict__ Wh,
    const float* __restrict__ pool, const float* __restrict__ cnt,
    const float* __restrict__ mol,
    const float* __restrict__ mlpb, const float* __restrict__ mlob,
    const float* __restrict__ gcnob,
    const float* __restrict__ pb1, const float* __restrict__ pb2,
    const float* __restrict__ oW, const float* __restrict__ ob,
    float* __restrict__ out, int G) {
    const int g0 = blockIdx.x * 16;
    const int t = threadIdx.x;
    const int lane = t & 63, wv = t >> 6;
    const int l15 = lane & 15, quad = lane >> 4;
    __shared__ unsigned short A[16][264], B[16][264], Cc[16][200], Mn[16][136];
    __shared__ float red[4][16];

    for (int i = t; i < 16 * 256; i += 256) {
        int g = i >> 8, k = i & 255;
        A[g][k] = f2bf(mol[(size_t)(g0 + g) * 256 + k]);
    }
    for (int i = t; i < 16 * 128; i += 256) {
        int g = i >> 7, k = i & 127;
        float c = cnt[g0 + g];
        Mn[g][k] = f2bf(pool[(size_t)(g0 + g) * 128 + k] / fmaxf(c, 1.f));
    }
    __syncthreads();

    // one 16x16 output tile: rows=graphs, cols=ocol..ocol+15 (lane col=l15)
    auto do_tile = [&](const unsigned short* actb, int astr, int K,
                       const unsigned short* W, int orow,
                       const float* __restrict__ bias, int bidx,
                       unsigned short* dstb, int dstr, int ocol, bool dorelu) {
        f32x4 c = {0.f, 0.f, 0.f, 0.f};
        for (int kt = 0; kt < (K >> 5); ++kt) {
            short8 af = *(const short8*)(actb + (size_t)l15 * astr + kt * 32 + quad * 8);
            short8 bf = *(const short8*)(W + (size_t)orow * K + kt * 32 + quad * 8);
            c = __builtin_amdgcn_mfma_f32_16x16x32_bf16(af, bf, c, 0, 0, 0);
        }
        float bb = bias[bidx];
        #pragma unroll
        for (int r = 0; r < 4; ++r) {
            int g = quad * 4 + r;
            float v = c[r] + bb;
            if (dorelu) v = fmaxf(v, 0.f);
            dstb[(size_t)g * dstr + ocol] = f2bf(v);
        }
    };

    // mlp0: A(K=256) -> B relu
    #pragma unroll
    for (int nt = 0; nt < 4; ++nt) {
        int o = (wv * 4 + nt) * 16 + l15;
        do_tile(&A[0][0], 264, 256, Wh + HW_MLP0, o, mlpb, o, &B[0][0], 264, o, true);
    }
    __syncthreads();
    // mlp1: B(K=256) -> A relu
    #pragma unroll
    for (int nt = 0; nt < 4; ++nt) {
        int o = (wv * 4 + nt) * 16 + l15;
        do_tile(&B[0][0], 264, 256, Wh + HW_MLP1, o, mlpb + 256, o, &A[0][0], 264, o, true);
    }
    __syncthreads();
    // concat -> Cc[16][192]: tiles 0..7 gcn_out (K=128 from Mn, no relu),
    // tiles 8..11 mlo (K=256 from A, relu, cols 128..191). Wave w: tiles 3w..3w+2.
    #pragma unroll
    for (int j = 0; j < 3; ++j) {
        int tile = wv * 3 + j;
        if (tile < 8) {
            int o = tile * 16 + l15;
            do_tile(&Mn[0][0], 136, 128, Wh + HW_GCNO, o, gcnob, o, &Cc[0][0], 200, o, false);
        } else {
            int om = (tile - 8) * 16 + l15;
            do_tile(&A[0][0], 264, 256, Wh + HW_MLO, om, mlob, om, &Cc[0][0], 200, 128 + om, true);
        }
    }
    __syncthreads();
    // pred1: Cc(K=192) -> B relu
    #pragma unroll
    for (int nt = 0; nt < 4; ++nt) {
        int o = (wv * 4 + nt) * 16 + l15;
        do_tile(&Cc[0][0], 200, 192, Wh + HW_PW1, o, pb1, o, &B[0][0], 264, o, true);
    }
    __syncthreads();
    // pred2 (K=256) fused with out-dot
    {
        float pacc[4] = {0.f, 0.f, 0.f, 0.f};
        #pragma unroll
        for (int nt = 0; nt < 4; ++nt) {
            int o = (wv * 4 + nt) * 16 + l15;
            f32x4 c = {0.f, 0.f, 0.f, 0.f};
            #pragma unroll
            for (int kt = 0; kt < 8; ++kt) {
                short8 af = *(const short8*)(&B[0][0] + (size_t)l15 * 264 + kt * 32 + quad * 8);
                short8 bf = *(const short8*)(Wh + HW_PW2 + (size_t)o * 256 + kt * 32 + quad * 8);
                c = __builtin_amdgcn_mfma_f32_16x16x32_bf16(af, bf, c, 0, 0, 0);
            }
            float bb = pb2[o], wo = oW[o];
            #pragma unroll
            for (int r = 0; r < 4; ++r)
                pacc[r] += fmaxf(c[r] + bb, 0.f) * wo;
        }
        // reduce over l15 (16 lanes within quad)
        #pragma unroll
        for (int off = 1; off < 16; off <<= 1)
            #pragma unroll
            for (int r = 0; r < 4; ++r)
                pacc[r] += __shfl_xor(pacc[r], off, 64);
        if (l15 == 0) {
            #pragma unroll
            for (int r = 0; r < 4; ++r)
                red[wv][quad * 4 + r] = pacc[r];
        }
    }
    __syncthreads();
    if (t < 16) {
        float s = red[0][t] + red[1][t] + red[2][t] + red[3][t] + ob[0];
        if (g0 + t < G) out[g0 + t] = s;
    }
}

extern "C" void kernel_launch(void* const* d_in, const int* in_sizes, int n_in,
                              void* d_out, int out_size, void* d_ws, size_t ws_size,
                              hipStream_t stream) {
    const float* x     = (const float*)d_in[0];
    const int*   ei    = (const int*)d_in[1];
    const int*   batch = (const int*)d_in[2];
    const float* mol   = (const float*)d_in[3];
    const float* gcnW  = (const float*)d_in[4];
    const float* gcnb  = (const float*)d_in[5];
    const float* gcnoW = (const float*)d_in[6];
    const float* gcnob = (const float*)d_in[7];
    const float* mlpW  = (const float*)d_in[8];
    const float* mlpb  = (const float*)d_in[9];
    const float* mloW  = (const float*)d_in[10];
    const float* mlob  = (const float*)d_in[11];
    const float* pW1   = (const float*)d_in[12];
    const float* pb1   = (const float*)d_in[13];
    const float* pW2   = (const float*)d_in[14];
    const float* pb2   = (const float*)d_in[15];
    const float* oW    = (const float*)d_in[16];
    const float* ob    = (const float*)d_in[17];

    const int N = in_sizes[0] / 128;
    const int E = in_sizes[1] / 2;
    const int G = in_sizes[3] / 256;
    const int* row = ei;
    const int* col = ei + E;

    const int NBK = (N + BKT - 1) / BKT;       // 782 buckets
    const int M = NBK * SL;                    // 12512 cells
    const int C = (E + NBINBLK - 1) / NBINBLK; // edges per bin block

    char* p = (char*)d_ws;
    auto alloc = [&](size_t bytes) {
        char* q = p;
        p += (bytes + 255) & ~(size_t)255;
        return (void*)q;
    };
    int*    rs    = (int*)alloc((size_t)NBK * 64 * 4);
    unsigned short* rd = (unsigned short*)alloc((size_t)NBK * 64 * 2);
    float*  dinv  = (float*)alloc((size_t)NBK * 64 * 4);
    int*    cur   = (int*)alloc((size_t)M * 16 * 4);   // line-padded cursors
    unsigned* gbin = (unsigned*)alloc((size_t)M * CAP * 4);
    unsigned short* csrf = (unsigned short*)alloc(((size_t)NBK * WCAP + 32) * 2);
    unsigned short* xb   = (unsigned short*)alloc((size_t)HROWS * 128 * 2);
    unsigned short* bufA = (unsigned short*)alloc((size_t)HROWS * 128 * 2);
    unsigned short* bufB = (unsigned short*)alloc((size_t)HROWS * 128 * 2);
    uint4*  Wb    = (uint4*)alloc((size_t)3 * 2048 * 16);
    unsigned short* Wh = (unsigned short*)alloc((size_t)HW_TOT * 2);
    float*  pool  = (float*)alloc((size_t)G * 128 * 4);
    float*  cnt   = (float*)alloc((size_t)G * 4);

    const int initblocks = (M * 16 + 255) / 256;   // covers cursors + casts

    k_init<<<initblocks, 256, 0, stream>>>(cur, pool, cnt, gcnW, Wb,
                                           mlpW, mloW, gcnoW, pW1, pW2, Wh,
                                           xb, bufA, bufB, batch, M, G, N);
    k_bin<<<NBINBLK, 256, 0, stream>>>(row, col, cur, gbin, E, C);
    k_csr<<<NBK, 256, 0, stream>>>(gbin, cur, rs, rd, dinv, csrf, x, xb, N);

    const int fblocks = (N + 63) / 64;
    // ping-pong: xb -> bufA -> bufB -> (pool)  (src and dst always distinct)
    k_fused<<<fblocks, 512, 0, stream>>>(xb, Wb, gcnb, dinv, dinv,
                                         rs, rd, csrf, bufA,
                                         batch, (float*)nullptr, N);
    k_fused<<<fblocks, 512, 0, stream>>>(bufA, Wb + 2048, gcnb + 128, dinv, dinv,
                                         rs, rd, csrf, bufB,
                                         batch, (float*)nullptr, N);
    k_fused<<<fblocks, 512, 0, stream>>>(bufB, Wb + 4096, gcnb + 256,
                                         (const float*)nullptr, dinv,
                                         rs, rd, csrf, bufA,
                                         batch, pool, N);
    k_head<<<(G + 15) / 16, 256, 0, stream>>>(
        Wh, pool, cnt, mol, mlpb, mlob, gcnob, pb1, pb2, oW, ob,
        (float*)d_out, G);
}

// Round 16
// 320.546 us; speedup vs baseline: 1.3021x; 1.3021x over previous
//
#include <hip/hip_runtime.h>

// ---------------------------------------------------------------------------
// GCN model, re-associated: per layer h = relu((A_hat @ h_prev) @ W^T + b);
// pool BEFORE gcn_out linear. Node features BF16 (fp32 accumulate), dinv
// folded into features. CSR via single-pass padded-region binning.
// FINAL = R9/R14 configuration (best, reproduced twice: 320.8 / 324.4us).
// Falsified alternatives (ledger):
//  R4  LDS f32 atomics accumulate: 14x slower (ds-atomic pipe serializes).
//  R6/R8/R15  >4 gather loads in flight: spills at every achievable VGPR
//      budget (64 @1024thr, 64 @512thr despite (512,4)) -> WRITE 95-166MB.
//  R9  LDS-ids staging: null alone (kept; off the vmcnt chain, harmless).
//  R10 L2 src-window blocking: null (compulsory XCD-wide footprint).
//  R11 cooperative mega-kernel: unified regalloc spills the gather.
//  R12/R13 R3-style wave-per-node loop: 63us now (unreproducible 47).
// Gather regime: L2-miss-latency-bound at 4 loads in flight/subgroup
// (~1.6TB/s of a >3.1TB/s fabric); 6 formulations all sticky at 55-63us.
// Residual: ~165us gather floor + ~75us preprocessing + ~80us dispatch gaps.
// ---------------------------------------------------------------------------

typedef __attribute__((ext_vector_type(8))) short short8;   // MFMA A/B frag
typedef __attribute__((ext_vector_type(4))) float f32x4;    // MFMA C/D frag

#define BKT 64        // nodes per bucket
#define SL 16         // slices per bucket
#define CAP 192       // capacity per (bucket,slice) cell   (Poisson 64)
#define WCAP 2560     // csrf window per bucket (padded degs; Poisson 1024)
#define NBINBLK 2048  // k_bin grid
#define HROWS 65536   // h-buffer rows allocated (row N = dummy zero row)

// Head-weight bf16 arena offsets (elements)
#define HW_MLP0 0
#define HW_MLP1 65536
#define HW_MLO  131072
#define HW_GCNO 147456
#define HW_PW1  163840
#define HW_PW2  212992
#define HW_TOT  278528

__device__ __forceinline__ unsigned short f2bf(float f) {
    union { float f; unsigned u; } c; c.f = f;
    unsigned u = c.u;
    unsigned r = u + 0x7FFFu + ((u >> 16) & 1u);   // RNE
    return (unsigned short)(r >> 16);
}
__device__ __forceinline__ float bflo(unsigned w) {
    union { unsigned u; float f; } c; c.u = w << 16; return c.f;
}
__device__ __forceinline__ float bfhi(unsigned w) {
    union { unsigned u; float f; } c; c.u = w & 0xFFFF0000u; return c.f;
}

// zero line-padded cursors, pool, dummy rows; cnt[g] via binary search on
// sorted batch (no atomics); cast gcn_W -> swizzled bf16; cast ALL head
// weights -> flat bf16 arena Wh.
__global__ void k_init(int* cur, float* pool, float* cnt,
                       const float* __restrict__ gcnW, uint4* __restrict__ Wb,
                       const float* __restrict__ mlpW, const float* __restrict__ mloW,
                       const float* __restrict__ gcnoW, const float* __restrict__ pW1,
                       const float* __restrict__ pW2, unsigned short* __restrict__ Wh,
                       unsigned short* xb, unsigned short* bufA, unsigned short* bufB,
                       const int* __restrict__ batch, int M, int G, int N) {
    int i = blockIdx.x * 256 + threadIdx.x;
    if (i < M * 16) cur[i] = 0;
    if (i < G * 128) pool[i] = 0.f;
    if (i < G) {
        // cnt[i] = #nodes with batch==i (batch sorted ascending)
        int lo = 0, hi = N;
        while (lo < hi) { int m = (lo + hi) >> 1; if (batch[m] < i) lo = m + 1; else hi = m; }
        int lo2 = lo, hi2 = N;
        while (lo2 < hi2) { int m = (lo2 + hi2) >> 1; if (batch[m] < i + 1) lo2 = m + 1; else hi2 = m; }
        cnt[i] = (float)(lo2 - lo);
    }
    if (i < 192) {                       // zero dummy row N of the 3 h-buffers
        unsigned short* b = (i < 64) ? xb : (i < 128) ? bufA : bufB;
        *(unsigned*)(b + (size_t)N * 128 + (i & 63) * 2) = 0u;
    }
    if (i < 3 * 2048) {                  // gcn W cast: chunk c=k/8, row o, layer l
        int l = i >> 11, rem = i & 2047;
        int o = rem >> 4, c = rem & 15;
        const float4* s = (const float4*)(gcnW + (size_t)l * 16384 + o * 128 + c * 8);
        float4 a = s[0], b = s[1];
        uint4 v;
        v.x = ((unsigned)f2bf(a.y) << 16) | f2bf(a.x);
        v.y = ((unsigned)f2bf(a.w) << 16) | f2bf(a.z);
        v.z = ((unsigned)f2bf(b.y) << 16) | f2bf(b.x);
        v.w = ((unsigned)f2bf(b.w) << 16) | f2bf(b.z);
        Wb[(l << 11) | (o << 4) | (c ^ (o & 15))] = v;
    }
    int j = i - 8192;                    // head-weight flat cast, 8 elems/thread
    if (j >= 0 && j < (HW_TOT / 8)) {
        int e = j * 8;
        const float* src;
        if (e < HW_MLO)        src = mlpW  + e;
        else if (e < HW_GCNO)  src = mloW  + (e - HW_MLO);
        else if (e < HW_PW1)   src = gcnoW + (e - HW_GCNO);
        else if (e < HW_PW2)   src = pW1   + (e - HW_PW1);
        else                   src = pW2   + (e - HW_PW2);
        float4 a = *(const float4*)src;
        float4 b = *((const float4*)src + 1);
        uint4 v;
        v.x = ((unsigned)f2bf(a.y) << 16) | f2bf(a.x);
        v.y = ((unsigned)f2bf(a.w) << 16) | f2bf(a.z);
        v.z = ((unsigned)f2bf(b.y) << 16) | f2bf(b.x);
        v.w = ((unsigned)f2bf(b.w) << 16) | f2bf(b.z);
        *(uint4*)(Wh + e) = v;
    }
}

// Single-pass binning. Cursor cell = cur[cell*16] (one 64B line per cell);
// gbin position = cell*CAP + count (closed form).
__global__ __launch_bounds__(256) void k_bin(const int* __restrict__ row,
                                             const int* __restrict__ col,
                                             int* __restrict__ cur,
                                             unsigned* __restrict__ gbin,
                                             int E, int C) {
    const int x = blockIdx.x & (SL - 1);
    int e0 = blockIdx.x * C, e1 = min(E, e0 + C);
    for (int e = e0 + threadIdx.x; e < e1; e += 256) {
        int c = col[e];
        int cell = (c >> 6) * SL + x;
        int cnt = atomicAdd(&cur[cell << 4], 1);
        gbin[cell * CAP + cnt] = (unsigned)row[e] | ((unsigned)(c & 63) << 16);
    }
}

// One block per bucket: LDS histogram of 64 dsts -> (start,deg,dinv) with
// degs PADDED to x8 in the prefix scan; scatter 2B src ids; fill pad slots
// with dummy src N; fused x->bf16*dinv cast.
__global__ __launch_bounds__(256) void k_csr(const unsigned* __restrict__ gbin,
                                             const int* __restrict__ cur,
                                             int* __restrict__ rs,
                                             unsigned short* __restrict__ rd,
                                             float* __restrict__ dinv,
                                             unsigned short* __restrict__ csrf,
                                             const float* __restrict__ x,
                                             unsigned short* __restrict__ xb,
                                             int N) {
    const int b = blockIdx.x, t = threadIdx.x;
    __shared__ int hcnt[64], lcur[64], fills[SL];
    __shared__ float sdinv[64];
    if (t < 64) hcnt[t] = 0;
    if (t < SL) fills[t] = cur[(b * SL + t) << 4];
    __syncthreads();
    #pragma unroll 4
    for (int xx = 0; xx < SL; ++xx) {
        int cbase = (b * SL + xx) * CAP, fill = fills[xx];
        for (int i = t; i < fill; i += 256)
            atomicAdd(&hcnt[(gbin[cbase + i] >> 16) & 63], 1);
    }
    __syncthreads();
    if (t < 64) {
        int v = hcnt[t];
        int vp = (v + 7) & ~7;          // padded degree
        int xs = vp;
        #pragma unroll
        for (int off = 1; off < 64; off <<= 1) {
            int u = __shfl_up(xs, off, 64);
            if (t >= off) xs += u;
        }
        int excl = xs - vp;             // padded exclusive prefix (x8 aligned)
        lcur[t] = excl;
        float d = rsqrtf((float)v + 1.0f);
        sdinv[t] = d;
        int node = b * 64 + t;          // rs/rd/dinv sized NBK*64: always safe
        rs[node] = b * WCAP + excl;
        rd[node] = (unsigned short)v;
        dinv[node] = d;
    }
    __syncthreads();
    #pragma unroll 4
    for (int xx = 0; xx < SL; ++xx) {
        int cbase = (b * SL + xx) * CAP, fill = fills[xx];
        for (int i = t; i < fill; i += 256) {
            unsigned v = gbin[cbase + i];
            int p = atomicAdd(&lcur[(v >> 16) & 63], 1);
            csrf[b * WCAP + p] = (unsigned short)(v & 0xFFFFu);
        }
    }
    __syncthreads();
    if (t < 64) {                        // fill pad slots with dummy src N
        int v = hcnt[t], vp = (v + 7) & ~7;
        int base = lcur[t];              // == excl + v after scatter
        for (int p = v; p < vp; ++p)
            csrf[b * WCAP + base + (p - v)] = (unsigned short)N;
    }
    // fused x -> bf16*dinv cast (64 nodes x 16 chunks)
    const int node0 = b * 64;
    #pragma unroll
    for (int it = 0; it < 4; ++it) {
        int i = t + it * 256;              // 0..1023
        int nd = node0 + (i >> 4);
        if (nd < N) {
            int ch = i & 15;
            float d = sdinv[i >> 4];
            const float4* s = (const float4*)(x + (size_t)nd * 128 + ch * 8);
            float4 a = s[0], bb = s[1];
            uint4 o;
            o.x = ((unsigned)f2bf(d * a.y) << 16) | f2bf(d * a.x);
            o.y = ((unsigned)f2bf(d * a.w) << 16) | f2bf(d * a.z);
            o.z = ((unsigned)f2bf(d * bb.y) << 16) | f2bf(d * bb.x);
            o.w = ((unsigned)f2bf(d * bb.w) << 16) | f2bf(d * bb.z);
            *(uint4*)(xb + (size_t)nd * 128 + ch * 8) = o;
        }
    }
}

// Fused per-layer kernel: block = 64 nodes = one MFMA tile, 1024 thr,
// 2 blocks/CU (launch_bounds(1024,8) -> 64 VGPR budget).
// Stage the block's padded edge-id window into LDS once (cooperative);
// gather loop reads ids via ds_read (lgkmcnt — off the vmcnt chain) and
// keeps 4 uint4 gathers in flight per iteration (proven spill-free width).
// MFMA: wave = (row-tile, col-pair); C = relu(A @ W^T + b) * dscale.
// l=2 (pool != nullptr): skip C store, atomic segment-sum into pool.
// h (input) and C (output) MUST be distinct buffers (launcher ping-pongs).
__global__ __launch_bounds__(1024, 8) void k_fused(
    const unsigned short* __restrict__ h,
    const uint4* __restrict__ Wb,
    const float* __restrict__ bias,
    const float* __restrict__ dscale,
    const float* __restrict__ dinv,
    const int* __restrict__ rs,
    const unsigned short* __restrict__ rd,
    const unsigned short* __restrict__ csrf,
    unsigned short* __restrict__ C,
    const int* __restrict__ batch,
    float* __restrict__ pool, int N) {
    __shared__ uint4 Wsh[2048];                 // 32 KB swizzled weights
    __shared__ unsigned short Ash[64][136];     // 17 KB padded A tile
    __shared__ unsigned short Ish[WCAP];        // 5 KB edge ids (padded x8)

    const int t = threadIdx.x;
    Wsh[t] = Wb[t];
    Wsh[t + 1024] = Wb[t + 1024];

    const int sub = t >> 4;                     // 0..63 subgroup = local row
    const int fg = t & 15;                      // feature group (8 elems)
    const int blk0 = blockIdx.x * 64;
    const int node = blk0 + sub;

    // ---- stage edge-id window into LDS (16B chunks, padded x8 -> exact) ----
    const int base = blockIdx.x * WCAP;
    const int ln = blk0 + 63;                   // rs/rd sized NBK*64: safe
    const int wcnt = (rs[ln] + ((rd[ln] + 7) & ~7)) - base;
    for (int i = t * 8; i < wcnt; i += 8192)
        *(uint4*)(&Ish[i]) = *(const uint4*)(csrf + base + i);
    __syncthreads();

    // ---- gather: acc in regs, self-row init; ids from LDS; 4-wide ----
    float acc[8] = {0.f, 0.f, 0.f, 0.f, 0.f, 0.f, 0.f, 0.f};
    const unsigned fgo = (unsigned)fg * 8u;
    if (node < N) {
        uint4 hv = *(const uint4*)(h + (size_t)node * 128u + fgo);
        acc[0] = bflo(hv.x); acc[1] = bfhi(hv.x);
        acc[2] = bflo(hv.y); acc[3] = bfhi(hv.y);
        acc[4] = bflo(hv.z); acc[5] = bfhi(hv.z);
        acc[6] = bflo(hv.w); acc[7] = bfhi(hv.w);
    }
    {
        const int stl = rs[node] - base;
        const int epl = stl + ((rd[node] + 7) & ~7);
        #pragma unroll 1
        for (int i = stl; i < epl; i += 4) {
            const uint2 iv = *(const uint2*)(&Ish[i]);   // 4 ids, ds_read_b64
            const uint4 v0 = *(const uint4*)(h + ((iv.x & 0xFFFFu) * 128u + fgo));
            const uint4 v1 = *(const uint4*)(h + ((iv.x >> 16)     * 128u + fgo));
            const uint4 v2 = *(const uint4*)(h + ((iv.y & 0xFFFFu) * 128u + fgo));
            const uint4 v3 = *(const uint4*)(h + ((iv.y >> 16)     * 128u + fgo));
            acc[0] += bflo(v0.x); acc[1] += bfhi(v0.x);
            acc[2] += bflo(v0.y); acc[3] += bfhi(v0.y);
            acc[4] += bflo(v0.z); acc[5] += bfhi(v0.z);
            acc[6] += bflo(v0.w); acc[7] += bfhi(v0.w);
            acc[0] += bflo(v1.x); acc[1] += bfhi(v1.x);
            acc[2] += bflo(v1.y); acc[3] += bfhi(v1.y);
            acc[4] += bflo(v1.z); acc[5] += bfhi(v1.z);
            acc[6] += bflo(v1.w); acc[7] += bfhi(v1.w);
            acc[0] += bflo(v2.x); acc[1] += bfhi(v2.x);
            acc[2] += bflo(v2.y); acc[3] += bfhi(v2.y);
            acc[4] += bflo(v2.z); acc[5] += bfhi(v2.z);
            acc[6] += bflo(v2.w); acc[7] += bfhi(v2.w);
            acc[0] += bflo(v3.x); acc[1] += bfhi(v3.x);
            acc[2] += bflo(v3.y); acc[3] += bfhi(v3.y);
            acc[4] += bflo(v3.z); acc[5] += bfhi(v3.z);
            acc[6] += bflo(v3.w); acc[7] += bfhi(v3.w);
        }
    }
    // ---- scale + pack to bf16 A-tile ----
    {
        const float dn = (node < N) ? dinv[node] : 0.f;
        unsigned short ob[8];
        #pragma unroll
        for (int j = 0; j < 8; ++j) ob[j] = f2bf(acc[j] * dn);
        uint4 o;
        o.x = ((unsigned)ob[1] << 16) | ob[0];
        o.y = ((unsigned)ob[3] << 16) | ob[2];
        o.z = ((unsigned)ob[5] << 16) | ob[4];
        o.w = ((unsigned)ob[7] << 16) | ob[6];
        *(uint4*)(&Ash[sub][fg * 8]) = o;
    }
    __syncthreads();

    // ---- MFMA ----
    const int lane = t & 63;
    const int wv = t >> 6;
    const int l15 = lane & 15, quad = lane >> 4;
    const int rt = wv & 3, cp = wv >> 2;
    f32x4 acc2[2];
    acc2[0] = (f32x4){0.f, 0.f, 0.f, 0.f};
    acc2[1] = (f32x4){0.f, 0.f, 0.f, 0.f};
    #pragma unroll
    for (int kiter = 0; kiter < 4; ++kiter) {
        short8 af = *(const short8*)(&Ash[rt * 16 + l15][kiter * 32 + quad * 8]);
        const int cswz = (kiter * 4 + quad) ^ l15;
        #pragma unroll
        for (int cc = 0; cc < 2; ++cc) {
            int ct = cp * 2 + cc;
            short8 bf = *(const short8*)(&Wsh[((ct * 16 + l15) << 4) | cswz]);
            acc2[cc] = __builtin_amdgcn_mfma_f32_16x16x32_bf16(af, bf, acc2[cc], 0, 0, 0);
        }
    }

    const int rbase = blk0 + rt * 16 + quad * 4;
    if (pool) {
        // l=2: relu + segment-sum into pool (rows sorted by graph)
        int gr[4];
        #pragma unroll
        for (int r = 0; r < 4; ++r)
            gr[r] = (rbase + r < N) ? batch[rbase + r] : -1;
        #pragma unroll
        for (int cc = 0; cc < 2; ++cc) {
            int colc = (cp * 2 + cc) * 16 + l15;
            float bcol = bias[colc];
            float s = 0.f; int gprev = -2;
            #pragma unroll
            for (int r = 0; r < 4; ++r) {
                if (gr[r] >= 0) {
                    float v = fmaxf(acc2[cc][r] + bcol, 0.f);
                    if (gr[r] == gprev) s += v;
                    else {
                        if (gprev >= 0) atomicAdd(&pool[(size_t)gprev * 128 + colc], s);
                        gprev = gr[r]; s = v;
                    }
                }
            }
            if (gprev >= 0) atomicAdd(&pool[(size_t)gprev * 128 + colc], s);
        }
    } else {
        float ds[4];
        #pragma unroll
        for (int r = 0; r < 4; ++r) {
            int rr = rbase + r;
            ds[r] = (dscale && rr < N) ? dscale[rr] : 1.f;
        }
        #pragma unroll
        for (int cc = 0; cc < 2; ++cc) {
            int colc = (cp * 2 + cc) * 16 + l15;
            float bcol = bias[colc];
            #pragma unroll
            for (int r = 0; r < 4; ++r) {
                int rr = rbase + r;
                if (rr < N) {
                    float v = fmaxf(acc2[cc][r] + bcol, 0.f) * ds[r];
                    C[(size_t)rr * 128 + colc] = f2bf(v);
                }
            }
        }
    }
}

// Fused head via MFMA: 16 graphs/block (M=16), 256 thr = 4 waves. Activations
// bf16 in LDS; B-frags from bf16 weight arena in global (L2-hot). Each wave
// owns 4 of 16 output-tiles per 256-out layer. fp32 accumulation throughout.
__global__ __launch_bounds__(256) void k_head(
    const unsigned short* __restrict__ Wh,
    const float* __restrict__ pool, const float* __restrict__ cnt,
    const float* __restrict__ mol,
    const float* __restrict__ mlpb, const float* __restrict__ mlob,
    const float* __restrict__ gcnob,
    const float* __restrict__ pb1, const float* __restrict__ pb2,
    const float* __restrict__ oW, const float* __restrict__ ob,
    float* __restrict__ out, int G) {
    const int g0 = blockIdx.x * 16;
    const int t = threadIdx.x;
    const int lane = t & 63, wv = t >> 6;
    const int l15 = lane & 15, quad = lane >> 4;
    __shared__ unsigned short A[16][264], B[16][264], Cc[16][200], Mn[16][136];
    __shared__ float red[4][16];

    for (int i = t; i < 16 * 256; i += 256) {
        int g = i >> 8, k = i & 255;
        A[g][k] = f2bf(mol[(size_t)(g0 + g) * 256 + k]);
    }
    for (int i = t; i < 16 * 128; i += 256) {
        int g = i >> 7, k = i & 127;
        float c = cnt[g0 + g];
        Mn[g][k] = f2bf(pool[(size_t)(g0 + g) * 128 + k] / fmaxf(c, 1.f));
    }
    __syncthreads();

    // one 16x16 output tile: rows=graphs, cols=ocol..ocol+15 (lane col=l15)
    auto do_tile = [&](const unsigned short* actb, int astr, int K,
                       const unsigned short* W, int orow,
                       const float* __restrict__ bias, int bidx,
                       unsigned short* dstb, int dstr, int ocol, bool dorelu) {
        f32x4 c = {0.f, 0.f, 0.f, 0.f};
        for (int kt = 0; kt < (K >> 5); ++kt) {
            short8 af = *(const short8*)(actb + (size_t)l15 * astr + kt * 32 + quad * 8);
            short8 bf = *(const short8*)(W + (size_t)orow * K + kt * 32 + quad * 8);
            c = __builtin_amdgcn_mfma_f32_16x16x32_bf16(af, bf, c, 0, 0, 0);
        }
        float bb = bias[bidx];
        #pragma unroll
        for (int r = 0; r < 4; ++r) {
            int g = quad * 4 + r;
            float v = c[r] + bb;
            if (dorelu) v = fmaxf(v, 0.f);
            dstb[(size_t)g * dstr + ocol] = f2bf(v);
        }
    };

    // mlp0: A(K=256) -> B relu
    #pragma unroll
    for (int nt = 0; nt < 4; ++nt) {
        int o = (wv * 4 + nt) * 16 + l15;
        do_tile(&A[0][0], 264, 256, Wh + HW_MLP0, o, mlpb, o, &B[0][0], 264, o, true);
    }
    __syncthreads();
    // mlp1: B(K=256) -> A relu
    #pragma unroll
    for (int nt = 0; nt < 4; ++nt) {
        int o = (wv * 4 + nt) * 16 + l15;
        do_tile(&B[0][0], 264, 256, Wh + HW_MLP1, o, mlpb + 256, o, &A[0][0], 264, o, true);
    }
    __syncthreads();
    // concat -> Cc[16][192]: tiles 0..7 gcn_out (K=128 from Mn, no relu),
    // tiles 8..11 mlo (K=256 from A, relu, cols 128..191). Wave w: tiles 3w..3w+2.
    #pragma unroll
    for (int j = 0; j < 3; ++j) {
        int tile = wv * 3 + j;
        if (tile < 8) {
            int o = tile * 16 + l15;
            do_tile(&Mn[0][0], 136, 128, Wh + HW_GCNO, o, gcnob, o, &Cc[0][0], 200, o, false);
        } else {
            int om = (tile - 8) * 16 + l15;
            do_tile(&A[0][0], 264, 256, Wh + HW_MLO, om, mlob, om, &Cc[0][0], 200, 128 + om, true);
        }
    }
    __syncthreads();
    // pred1: Cc(K=192) -> B relu
    #pragma unroll
    for (int nt = 0; nt < 4; ++nt) {
        int o = (wv * 4 + nt) * 16 + l15;
        do_tile(&Cc[0][0], 200, 192, Wh + HW_PW1, o, pb1, o, &B[0][0], 264, o, true);
    }
    __syncthreads();
    // pred2 (K=256) fused with out-dot
    {
        float pacc[4] = {0.f, 0.f, 0.f, 0.f};
        #pragma unroll
        for (int nt = 0; nt < 4; ++nt) {
            int o = (wv * 4 + nt) * 16 + l15;
            f32x4 c = {0.f, 0.f, 0.f, 0.f};
            #pragma unroll
            for (int kt = 0; kt < 8; ++kt) {
                short8 af = *(const short8*)(&B[0][0] + (size_t)l15 * 264 + kt * 32 + quad * 8);
                short8 bf = *(const short8*)(Wh + HW_PW2 + (size_t)o * 256 + kt * 32 + quad * 8);
                c = __builtin_amdgcn_mfma_f32_16x16x32_bf16(af, bf, c, 0, 0, 0);
            }
            float bb = pb2[o], wo = oW[o];
            #pragma unroll
            for (int r = 0; r < 4; ++r)
                pacc[r] += fmaxf(c[r] + bb, 0.f) * wo;
        }
        // reduce over l15 (16 lanes within quad)
        #pragma unroll
        for (int off = 1; off < 16; off <<= 1)
            #pragma unroll
            for (int r = 0; r < 4; ++r)
                pacc[r] += __shfl_xor(pacc[r], off, 64);
        if (l15 == 0) {
            #pragma unroll
            for (int r = 0; r < 4; ++r)
                red[wv][quad * 4 + r] = pacc[r];
        }
    }
    __syncthreads();
    if (t < 16) {
        float s = red[0][t] + red[1][t] + red[2][t] + red[3][t] + ob[0];
        if (g0 + t < G) out[g0 + t] = s;
    }
}

extern "C" void kernel_launch(void* const* d_in, const int* in_sizes, int n_in,
                              void* d_out, int out_size, void* d_ws, size_t ws_size,
                              hipStream_t stream) {
    const float* x     = (const float*)d_in[0];
    const int*   ei    = (const int*)d_in[1];
    const int*   batch = (const int*)d_in[2];
    const float* mol   = (const float*)d_in[3];
    const float* gcnW  = (const float*)d_in[4];
    const float* gcnb  = (const float*)d_in[5];
    const float* gcnoW = (const float*)d_in[6];
    const float* gcnob = (const float*)d_in[7];
    const float* mlpW  = (const float*)d_in[8];
    const float* mlpb  = (const float*)d_in[9];
    const float* mloW  = (const float*)d_in[10];
    const float* mlob  = (const float*)d_in[11];
    const float* pW1   = (const float*)d_in[12];
    const float* pb1   = (const float*)d_in[13];
    const float* pW2   = (const float*)d_in[14];
    const float* pb2   = (const float*)d_in[15];
    const float* oW    = (const float*)d_in[16];
    const float* ob    = (const float*)d_in[17];

    const int N = in_sizes[0] / 128;
    const int E = in_sizes[1] / 2;
    const int G = in_sizes[3] / 256;
    const int* row = ei;
    const int* col = ei + E;

    const int NBK = (N + BKT - 1) / BKT;       // 782 buckets
    const int M = NBK * SL;                    // 12512 cells
    const int C = (E + NBINBLK - 1) / NBINBLK; // edges per bin block

    char* p = (char*)d_ws;
    auto alloc = [&](size_t bytes) {
        char* q = p;
        p += (bytes + 255) & ~(size_t)255;
        return (void*)q;
    };
    int*    rs    = (int*)alloc((size_t)NBK * 64 * 4);
    unsigned short* rd = (unsigned short*)alloc((size_t)NBK * 64 * 2);
    float*  dinv  = (float*)alloc((size_t)NBK * 64 * 4);
    int*    cur   = (int*)alloc((size_t)M * 16 * 4);   // line-padded cursors
    unsigned* gbin = (unsigned*)alloc((size_t)M * CAP * 4);
    unsigned short* csrf = (unsigned short*)alloc(((size_t)NBK * WCAP + 32) * 2);
    unsigned short* xb   = (unsigned short*)alloc((size_t)HROWS * 128 * 2);
    unsigned short* bufA = (unsigned short*)alloc((size_t)HROWS * 128 * 2);
    unsigned short* bufB = (unsigned short*)alloc((size_t)HROWS * 128 * 2);
    uint4*  Wb    = (uint4*)alloc((size_t)3 * 2048 * 16);
    unsigned short* Wh = (unsigned short*)alloc((size_t)HW_TOT * 2);
    float*  pool  = (float*)alloc((size_t)G * 128 * 4);
    float*  cnt   = (float*)alloc((size_t)G * 4);

    const int initblocks = (M * 16 + 255) / 256;   // covers cursors + casts

    k_init<<<initblocks, 256, 0, stream>>>(cur, pool, cnt, gcnW, Wb,
                                           mlpW, mloW, gcnoW, pW1, pW2, Wh,
                                           xb, bufA, bufB, batch, M, G, N);
    k_bin<<<NBINBLK, 256, 0, stream>>>(row, col, cur, gbin, E, C);
    k_csr<<<NBK, 256, 0, stream>>>(gbin, cur, rs, rd, dinv, csrf, x, xb, N);

    const int fblocks = (N + 63) / 64;
    // ping-pong: xb -> bufA -> bufB -> (pool)  (src and dst always distinct)
    k_fused<<<fblocks, 1024, 0, stream>>>(xb, Wb, gcnb, dinv, dinv,
                                          rs, rd, csrf, bufA,
                                          batch, (float*)nullptr, N);
    k_fused<<<fblocks, 1024, 0, stream>>>(bufA, Wb + 2048, gcnb + 128, dinv, dinv,
                                          rs, rd, csrf, bufB,
                                          batch, (float*)nullptr, N);
    k_fused<<<fblocks, 1024, 0, stream>>>(bufB, Wb + 4096, gcnb + 256,
                                          (const float*)nullptr, dinv,
                                          rs, rd, csrf, bufA,
                                          batch, pool, N);
    k_head<<<(G + 15) / 16, 256, 0, stream>>>(
        Wh, pool, cnt, mol, mlpb, mlob, gcnob, pb1, pb2, oW, ob,
        (float*)d_out, G);
}